// Round 1
// baseline (177.926 us; speedup 1.0000x reference)
//
#include <hip/hip_runtime.h>
#include <stdint.h>
#include <stddef.h>

// GraphCoarsenLayer: out = x@W_self + mean(x[nbr[:, :16]])@W_neigh
//                        + mean(x[nbr[:,16:]])@W_coarsen + (b_self+b_neigh+b_coarsen)
// Strategy: build A = [x | agg_s | agg_u] in bf16 (N x 768), W packed bf16 (768 x 256),
// single fused MFMA GEMM K=768.

#define NN   50000
#define NPAD 50048          // multiple of 128
#define KDIM 768
#define ODIM 256

typedef __bf16 bf16x8 __attribute__((ext_vector_type(8)));
typedef float  f32x4  __attribute__((ext_vector_type(4)));
typedef float  f32x4v __attribute__((ext_vector_type(4)));
typedef unsigned short u16x8 __attribute__((ext_vector_type(8)));
typedef unsigned short u16x4 __attribute__((ext_vector_type(4)));

static __device__ __forceinline__ unsigned short f2b(float f) {
    unsigned u = __builtin_bit_cast(unsigned, f);
    u += 0x7fffu + ((u >> 16) & 1u);          // round-to-nearest-even
    return (unsigned short)(u >> 16);
}
static __device__ __forceinline__ float b2f(unsigned short h) {
    unsigned u = ((unsigned)h) << 16;
    return __builtin_bit_cast(float, u);
}

// ---------------- kernel 1: pack weights (K-chunked layout) + bias sum ----------
// Wb element layout: [(t*8+kc)*256 + n]*8 + j   where k = t*64 + kc*8 + j
// This is exactly the order global_load_lds staging consumes (16B/lane contiguous).
__global__ void k_prep_w(const float* __restrict__ Wself, const float* __restrict__ bself,
                         const float* __restrict__ Wneigh, const float* __restrict__ bneigh,
                         const float* __restrict__ Wcoar, const float* __restrict__ bcoar,
                         unsigned short* __restrict__ Wb, float* __restrict__ bias) {
    int k = blockIdx.x;      // 0..767
    int n = threadIdx.x;     // 0..255
    const float* W = (k < 256) ? Wself : (k < 512) ? Wneigh : Wcoar;
    int kl = k & 255;
    float v = W[(size_t)kl * ODIM + n];
    int t  = k >> 6;
    int kc = (k >> 3) & 7;
    int j  = k & 7;
    Wb[(((size_t)(t * 8 + kc)) * ODIM + n) * 8 + j] = f2b(v);
    if (k == 0) bias[n] = bself[n] + bneigh[n] + bcoar[n];
}

// ---------------- kernel 2: x (f32) -> A[:, 0:256] (bf16) ----------------------
__global__ void k_convert_x(const float* __restrict__ x, unsigned short* __restrict__ A) {
    int p = blockIdx.x * 256 + threadIdx.x;    // one 8-element chunk per thread
    if (p >= NN * 32) return;
    int i  = p >> 5;
    int c8 = p & 31;
    const f32x4v* src = (const f32x4v*)(x + (size_t)i * 256 + c8 * 8);
    f32x4v v0 = src[0], v1 = src[1];
    u16x8 o;
    o[0] = f2b(v0[0]); o[1] = f2b(v0[1]); o[2] = f2b(v0[2]); o[3] = f2b(v0[3]);
    o[4] = f2b(v1[0]); o[5] = f2b(v1[1]); o[6] = f2b(v1[2]); o[7] = f2b(v1[3]);
    *(u16x8*)(A + (size_t)i * KDIM + c8 * 8) = o;
}

// ---------------- kernel 3: gather-mean -> A[:, 256:768] (bf16) ----------------
// One wave per node; lane owns 4 columns (8B loads). Reads bf16 x from A[:,0:256].
__global__ void k_gather(const int* __restrict__ nbr, unsigned short* __restrict__ A) {
    int wid  = threadIdx.x >> 6;
    int lane = threadIdx.x & 63;
    int i = blockIdx.x * 4 + wid;              // NN = 12500*4 exactly
    const int* nb = nbr + (size_t)i * 32;
    float s0 = 0, s1 = 0, s2 = 0, s3 = 0, u0 = 0, u1 = 0, u2 = 0, u3 = 0;
#pragma unroll
    for (int j = 0; j < 32; ++j) {
        int idx = nb[j];
        u16x4 v = *(const u16x4*)(A + (size_t)idx * KDIM + lane * 4);
        float f0 = b2f(v[0]), f1 = b2f(v[1]), f2 = b2f(v[2]), f3 = b2f(v[3]);
        if (j < 16) { s0 += f0; s1 += f1; s2 += f2; s3 += f3; }
        else        { u0 += f0; u1 += f1; u2 += f2; u3 += f3; }
    }
    const float r = 1.0f / 16.0f;
    u16x4 os = { f2b(s0 * r), f2b(s1 * r), f2b(s2 * r), f2b(s3 * r) };
    u16x4 ou = { f2b(u0 * r), f2b(u1 * r), f2b(u2 * r), f2b(u3 * r) };
    *(u16x4*)(A + (size_t)i * KDIM + 256 + lane * 4) = os;
    *(u16x4*)(A + (size_t)i * KDIM + 512 + lane * 4) = ou;
}

// ---------------- kernel 4: GEMM  out[N,256] = A[N,768] @ Wb + bias ------------
// 128x128 tile, BK=64, 4 waves (2x2), each wave 64x64 via 4x4 mfma_16x16x32_bf16.
// LDS K-chunked [kc][m][j] -> conflict-free ds_read_b128, linear global_load_lds dest.
#define BM 128
#define BN 128
#define BK 64

__global__ __launch_bounds__(256, 2) void k_gemm(const unsigned short* __restrict__ A,
                                                 const unsigned short* __restrict__ Wb,
                                                 const float* __restrict__ bias,
                                                 float* __restrict__ out) {
    __shared__ __align__(16) unsigned short lds[2][2][8192];  // [buf][A/B][128*64] = 64KB
    const int tid  = threadIdx.x;
    const int wid  = tid >> 6;
    const int lane = tid & 63;
    const int bid  = blockIdx.x;
    const int mt = bid >> 1, nt = bid & 1;
    const int row0 = mt * BM;
    const int n0   = nt * BN;
    const int wm = (wid >> 1) * 64, wn = (wid & 1) * 64;
    const int l15 = lane & 15, l4 = lane >> 4;

    f32x4 acc[4][4] = {};

    const int NT = KDIM / BK;  // 12

    auto stage = [&](int buf, int t) {
        const int k0 = t * BK;
#pragma unroll
        for (int q8 = 0; q8 < 8; ++q8) {
            const int q    = (wid & 1) * 8 + q8;   // 0..15
            const int kc   = q >> 1;
            const int half = q & 1;
            if (wid < 2) {
                const unsigned short* src =
                    A + (size_t)(row0 + half * 64 + lane) * KDIM + k0 + kc * 8;
                unsigned short* dst = &lds[buf][0][kc * 1024 + half * 512];
                __builtin_amdgcn_global_load_lds(
                    (const __attribute__((address_space(1))) void*)src,
                    (__attribute__((address_space(3))) void*)dst, 16, 0, 0);
            } else {
                const unsigned short* src =
                    Wb + (((size_t)(t * 8 + kc)) * ODIM + n0 + half * 64 + lane) * 8;
                unsigned short* dst = &lds[buf][1][kc * 1024 + half * 512];
                __builtin_amdgcn_global_load_lds(
                    (const __attribute__((address_space(1))) void*)src,
                    (__attribute__((address_space(3))) void*)dst, 16, 0, 0);
            }
        }
    };

    stage(0, 0);
    __syncthreads();
    int cur = 0;
    for (int t = 0; t < NT; ++t) {
        if (t + 1 < NT) stage(cur ^ 1, t + 1);   // loads fly during compute
#pragma unroll
        for (int kh = 0; kh < 2; ++kh) {         // kk = kh*32
            const int cb = kh * 4 + l4;          // k-chunk index
            bf16x8 af[4], bfr[4];
#pragma unroll
            for (int mi = 0; mi < 4; ++mi)
                af[mi] = *(const bf16x8*)&lds[cur][0][cb * 1024 + (wm + mi * 16 + l15) * 8];
#pragma unroll
            for (int ni = 0; ni < 4; ++ni)
                bfr[ni] = *(const bf16x8*)&lds[cur][1][cb * 1024 + (wn + ni * 16 + l15) * 8];
#pragma unroll
            for (int mi = 0; mi < 4; ++mi)
#pragma unroll
                for (int ni = 0; ni < 4; ++ni)
                    acc[mi][ni] = __builtin_amdgcn_mfma_f32_16x16x32_bf16(
                        af[mi], bfr[ni], acc[mi][ni], 0, 0, 0);
        }
        __syncthreads();                         // drains vmcnt -> next buffer ready
        cur ^= 1;
    }

    // epilogue: D[row][col], col = lane&15, row = (lane>>4)*4 + r  (verified layout)
#pragma unroll
    for (int mi = 0; mi < 4; ++mi) {
        const int row = row0 + wm + mi * 16 + l4 * 4;
#pragma unroll
        for (int ni = 0; ni < 4; ++ni) {
            const int col = n0 + wn + ni * 16 + l15;
            const float bb = bias[col];
            f32x4 v = acc[mi][ni];
#pragma unroll
            for (int r = 0; r < 4; ++r) {
                const int rr = row + r;
                if (rr < NN) out[(size_t)rr * ODIM + col] = v[r] + bb;
            }
        }
    }
}

// ---------------- launch -------------------------------------------------------
extern "C" void kernel_launch(void* const* d_in, const int* in_sizes, int n_in,
                              void* d_out, int out_size, void* d_ws, size_t ws_size,
                              hipStream_t stream) {
    const float* x      = (const float*)d_in[0];
    const float* Wself  = (const float*)d_in[1];
    const float* bself  = (const float*)d_in[2];
    const float* Wneigh = (const float*)d_in[3];
    const float* bneigh = (const float*)d_in[4];
    const float* Wcoar  = (const float*)d_in[5];
    const float* bcoar  = (const float*)d_in[6];
    const int*   nbr    = (const int*)d_in[7];
    float* out = (float*)d_out;

    // workspace layout (needs ~77.3 MB)
    unsigned short* A    = (unsigned short*)d_ws;                  // NPAD x 768 bf16
    unsigned short* Wb   = A + (size_t)NPAD * KDIM;                // 768 x 256 bf16 (packed)
    float*          bias = (float*)(Wb + (size_t)KDIM * ODIM);     // 256 f32

    k_prep_w<<<768, 256, 0, stream>>>(Wself, bself, Wneigh, bneigh, Wcoar, bcoar, Wb, bias);
    k_convert_x<<<(NN * 32 + 255) / 256, 256, 0, stream>>>(x, A);
    k_gather<<<NN / 4, 256, 0, stream>>>(nbr, A);
    k_gemm<<<(NPAD / BM) * 2, 256, 0, stream>>>(A, Wb, bias, out);
}

// Round 2
// 123.490 us; speedup vs baseline: 1.4408x; 1.4408x over previous
//
#include <hip/hip_runtime.h>
#include <stdint.h>
#include <stddef.h>

// GraphCoarsenLayer: out = x@W_self + mean(x[nbr[:, :16]])@W_neigh
//                        + mean(x[nbr[:,16:]])@W_coarsen + (b_self+b_neigh+b_coarsen)
// A = [x_bf16 | agg_s | agg_u] (N x 768), W packed bf16 (768 x 256), fused MFMA GEMM.
// Gather reads an fp8-e4m3 copy of x (halves the L2/L3-BW-bound gather traffic).

#define NN   50000
#define NPAD 50048          // multiple of 128
#define KDIM 768
#define ODIM 256

typedef __bf16 bf16x8 __attribute__((ext_vector_type(8)));
typedef float  f32x4  __attribute__((ext_vector_type(4)));
typedef float  f32x2  __attribute__((ext_vector_type(2)));
typedef unsigned short u16x8 __attribute__((ext_vector_type(8)));
typedef unsigned short u16x4 __attribute__((ext_vector_type(4)));

static __device__ __forceinline__ unsigned short f2b(float f) {
    unsigned u = __builtin_bit_cast(unsigned, f);
    u += 0x7fffu + ((u >> 16) & 1u);          // round-to-nearest-even
    return (unsigned short)(u >> 16);
}
static __device__ __forceinline__ float b2f(unsigned short h) {
    unsigned u = ((unsigned)h) << 16;
    return __builtin_bit_cast(float, u);
}

// ---------------- kernel 1: pack weights (K-chunked layout) + bias sum ----------
__global__ void k_prep_w(const float* __restrict__ Wself, const float* __restrict__ bself,
                         const float* __restrict__ Wneigh, const float* __restrict__ bneigh,
                         const float* __restrict__ Wcoar, const float* __restrict__ bcoar,
                         unsigned short* __restrict__ Wb, float* __restrict__ bias) {
    int k = blockIdx.x;      // 0..767
    int n = threadIdx.x;     // 0..255
    const float* W = (k < 256) ? Wself : (k < 512) ? Wneigh : Wcoar;
    int kl = k & 255;
    float v = W[(size_t)kl * ODIM + n];
    int t  = k >> 6;
    int kc = (k >> 3) & 7;
    int j  = k & 7;
    Wb[(((size_t)(t * 8 + kc)) * ODIM + n) * 8 + j] = f2b(v);
    if (k == 0) bias[n] = bself[n] + bneigh[n] + bcoar[n];
}

// ---------------- kernel 2: x (f32) -> A[:,0:256] bf16  (+ optional fp8 copy) ---
template <int FP8>
__global__ void k_convert_x(const float* __restrict__ x, unsigned short* __restrict__ A,
                            unsigned char* __restrict__ X8) {
    int p = blockIdx.x * 256 + threadIdx.x;    // one 8-element chunk per thread
    if (p >= NN * 32) return;
    int i  = p >> 5;
    int c8 = p & 31;
    const f32x4* src = (const f32x4*)(x + (size_t)i * 256 + c8 * 8);
    f32x4 v0 = src[0], v1 = src[1];
    u16x8 o;
    o[0] = f2b(v0[0]); o[1] = f2b(v0[1]); o[2] = f2b(v0[2]); o[3] = f2b(v0[3]);
    o[4] = f2b(v1[0]); o[5] = f2b(v1[1]); o[6] = f2b(v1[2]); o[7] = f2b(v1[3]);
    *(u16x8*)(A + (size_t)i * KDIM + c8 * 8) = o;
    if (FP8) {
        unsigned d0 = __builtin_amdgcn_cvt_pk_fp8_f32(v0[0], v0[1], 0, false);
        d0 = (unsigned)__builtin_amdgcn_cvt_pk_fp8_f32(v0[2], v0[3], d0, true);
        unsigned d1 = __builtin_amdgcn_cvt_pk_fp8_f32(v1[0], v1[1], 0, false);
        d1 = (unsigned)__builtin_amdgcn_cvt_pk_fp8_f32(v1[2], v1[3], d1, true);
        uint2 o8; o8.x = d0; o8.y = d1;
        *(uint2*)(X8 + (size_t)i * 256 + c8 * 8) = o8;
    }
}

// ---------------- kernel 3: gather-mean -> A[:, 256:768] (bf16) ----------------
// One wave per node; lane owns 4 columns. FP8 path: dword load (4 fp8) per
// neighbor; bf16 fallback: u16x4 load.
template <int FP8>
__global__ void k_gather(const int* __restrict__ nbr, const unsigned char* __restrict__ X8,
                         unsigned short* __restrict__ A) {
    int wid  = threadIdx.x >> 6;
    int lane = threadIdx.x & 63;
    int i = blockIdx.x * 4 + wid;              // NN = 12500*4 exactly
    const int* nb = nbr + (size_t)i * 32;
    float s0 = 0, s1 = 0, s2 = 0, s3 = 0, u0 = 0, u1 = 0, u2 = 0, u3 = 0;
#pragma unroll
    for (int j = 0; j < 32; ++j) {
        int idx = nb[j];
        float f0, f1, f2, f3;
        if (FP8) {
            unsigned d = *(const unsigned*)(X8 + (size_t)idx * 256 + lane * 4);
            f32x2 lo = __builtin_amdgcn_cvt_pk_f32_fp8(d, false);
            f32x2 hi = __builtin_amdgcn_cvt_pk_f32_fp8(d, true);
            f0 = lo[0]; f1 = lo[1]; f2 = hi[0]; f3 = hi[1];
        } else {
            u16x4 v = *(const u16x4*)(A + (size_t)idx * KDIM + lane * 4);
            f0 = b2f(v[0]); f1 = b2f(v[1]); f2 = b2f(v[2]); f3 = b2f(v[3]);
        }
        if (j < 16) { s0 += f0; s1 += f1; s2 += f2; s3 += f3; }
        else        { u0 += f0; u1 += f1; u2 += f2; u3 += f3; }
    }
    const float r = 1.0f / 16.0f;
    u16x4 os = { f2b(s0 * r), f2b(s1 * r), f2b(s2 * r), f2b(s3 * r) };
    u16x4 ou = { f2b(u0 * r), f2b(u1 * r), f2b(u2 * r), f2b(u3 * r) };
    *(u16x4*)(A + (size_t)i * KDIM + 256 + lane * 4) = os;
    *(u16x4*)(A + (size_t)i * KDIM + 512 + lane * 4) = ou;
}

// ---------------- kernel 4: GEMM  out[N,256] = A[N,768] @ Wb + bias ------------
#define BM 128
#define BN 128
#define BK 64

__global__ __launch_bounds__(256, 2) void k_gemm(const unsigned short* __restrict__ A,
                                                 const unsigned short* __restrict__ Wb,
                                                 const float* __restrict__ bias,
                                                 float* __restrict__ out) {
    __shared__ __align__(16) unsigned short lds[2][2][8192];  // [buf][A/B][128*64] = 64KB
    const int tid  = threadIdx.x;
    const int wid  = tid >> 6;
    const int lane = tid & 63;
    const int bid  = blockIdx.x;
    const int mt = bid >> 1, nt = bid & 1;
    const int row0 = mt * BM;
    const int n0   = nt * BN;
    const int wm = (wid >> 1) * 64, wn = (wid & 1) * 64;
    const int l15 = lane & 15, l4 = lane >> 4;

    f32x4 acc[4][4] = {};

    const int NT = KDIM / BK;  // 12

    auto stage = [&](int buf, int t) {
        const int k0 = t * BK;
#pragma unroll
        for (int q8 = 0; q8 < 8; ++q8) {
            const int q    = (wid & 1) * 8 + q8;   // 0..15
            const int kc   = q >> 1;
            const int half = q & 1;
            if (wid < 2) {
                const unsigned short* src =
                    A + (size_t)(row0 + half * 64 + lane) * KDIM + k0 + kc * 8;
                unsigned short* dst = &lds[buf][0][kc * 1024 + half * 512];
                __builtin_amdgcn_global_load_lds(
                    (const __attribute__((address_space(1))) void*)src,
                    (__attribute__((address_space(3))) void*)dst, 16, 0, 0);
            } else {
                const unsigned short* src =
                    Wb + (((size_t)(t * 8 + kc)) * ODIM + n0 + half * 64 + lane) * 8;
                unsigned short* dst = &lds[buf][1][kc * 1024 + half * 512];
                __builtin_amdgcn_global_load_lds(
                    (const __attribute__((address_space(1))) void*)src,
                    (__attribute__((address_space(3))) void*)dst, 16, 0, 0);
            }
        }
    };

    stage(0, 0);
    __syncthreads();
    int cur = 0;
    for (int t = 0; t < NT; ++t) {
        if (t + 1 < NT) stage(cur ^ 1, t + 1);   // loads fly during compute
#pragma unroll
        for (int kh = 0; kh < 2; ++kh) {         // kk = kh*32
            const int cb = kh * 4 + l4;          // k-chunk index
            bf16x8 af[4], bfr[4];
#pragma unroll
            for (int mi = 0; mi < 4; ++mi)
                af[mi] = *(const bf16x8*)&lds[cur][0][cb * 1024 + (wm + mi * 16 + l15) * 8];
#pragma unroll
            for (int ni = 0; ni < 4; ++ni)
                bfr[ni] = *(const bf16x8*)&lds[cur][1][cb * 1024 + (wn + ni * 16 + l15) * 8];
#pragma unroll
            for (int mi = 0; mi < 4; ++mi)
#pragma unroll
                for (int ni = 0; ni < 4; ++ni)
                    acc[mi][ni] = __builtin_amdgcn_mfma_f32_16x16x32_bf16(
                        af[mi], bfr[ni], acc[mi][ni], 0, 0, 0);
        }
        __syncthreads();                         // drains vmcnt -> next buffer ready
        cur ^= 1;
    }

    // epilogue: D[row][col], col = lane&15, row = (lane>>4)*4 + r
#pragma unroll
    for (int mi = 0; mi < 4; ++mi) {
        const int row = row0 + wm + mi * 16 + l4 * 4;
#pragma unroll
        for (int ni = 0; ni < 4; ++ni) {
            const int col = n0 + wn + ni * 16 + l15;
            const float bb = bias[col];
            f32x4 v = acc[mi][ni];
#pragma unroll
            for (int r = 0; r < 4; ++r) {
                const int rr = row + r;
                if (rr < NN) out[(size_t)rr * ODIM + col] = v[r] + bb;
            }
        }
    }
}

// ---------------- launch -------------------------------------------------------
extern "C" void kernel_launch(void* const* d_in, const int* in_sizes, int n_in,
                              void* d_out, int out_size, void* d_ws, size_t ws_size,
                              hipStream_t stream) {
    const float* x      = (const float*)d_in[0];
    const float* Wself  = (const float*)d_in[1];
    const float* bself  = (const float*)d_in[2];
    const float* Wneigh = (const float*)d_in[3];
    const float* bneigh = (const float*)d_in[4];
    const float* Wcoar  = (const float*)d_in[5];
    const float* bcoar  = (const float*)d_in[6];
    const int*   nbr    = (const int*)d_in[7];
    float* out = (float*)d_out;

    // workspace layout
    unsigned short* A    = (unsigned short*)d_ws;                  // NPAD x 768 bf16
    unsigned short* Wb   = A + (size_t)NPAD * KDIM;                // 768 x 256 bf16 (packed)
    float*          bias = (float*)(Wb + (size_t)KDIM * ODIM);     // 256 f32
    unsigned char*  X8   = (unsigned char*)(bias + 256);           // NN x 256 fp8 (optional)

    const size_t need_fp8 = (size_t)NPAD * KDIM * 2 + (size_t)KDIM * ODIM * 2
                          + 256 * 4 + (size_t)NN * 256;            // ~90.1 MB
    const bool fp8 = ws_size >= need_fp8;

    k_prep_w<<<768, 256, 0, stream>>>(Wself, bself, Wneigh, bneigh, Wcoar, bcoar, Wb, bias);
    if (fp8) {
        k_convert_x<1><<<(NN * 32 + 255) / 256, 256, 0, stream>>>(x, A, X8);
        k_gather<1><<<NN / 4, 256, 0, stream>>>(nbr, X8, A);
    } else {
        k_convert_x<0><<<(NN * 32 + 255) / 256, 256, 0, stream>>>(x, A, X8);
        k_gather<0><<<NN / 4, 256, 0, stream>>>(nbr, X8, A);
    }
    k_gemm<<<(NPAD / BM) * 2, 256, 0, stream>>>(A, Wb, bias, out);
}